// Round 15
// baseline (5701.516 us; speedup 1.0000x reference)
//
#include <hip/hip_runtime.h>

// LSTMAutoEncoder: B=64, T=512, H=512, F=32.
// Dead-code: only encoder L0 (final h,c) and decoder L0 feed the output:
//   out[:, t, :] = h_dec0_before_step(511-t) @ W_out^T + b_out
// -> 1024 sequential cell steps.
//
// Round 15: DUAL-POD STAGGER. 16 pods of 4 batch rows; each block serves two
// pods (pp, pp+8) in alternating half-iterations (hi even -> pod A at step
// sg=hi>>1; hi odd -> pod B at same sg). A pod's gather loads are issued at
// the END of the OTHER pod's half-iter (~1us after its own publish) -> tags
// arrive fresh; the MALL round trip hides under the other recurrence's
// compute. Per-pod protocol = r14 exactly: parity-2 pub planes, mantissa-tag
// u32 publishes ({f32 h, low byte = (sg+1)&255}), publish-post-BAR induction
// (a producer cannot be 2 steps ahead, so '== tag' spins always terminate).
// 4-row simplifications: out-proj = wave w does row w's full 512-dot + shfl
// (OP3/deferral/epilogue deleted); gather = 4 chunk-waits of 1 u64/lane.
// Weights shared by both pods (same VGPRs). Packed f2v FMA as r14.

#define TT   512
#define HH   512
#define FF   32
#define KP   548              // U row stride (floats): 512 h + 32 x + pad
#define NTHR 256
#define NBLK 256
#define GRS  66               // Gr batch-row stride (64 gates + 2 pad)
#define GPL4 272              // per-ks plane stride (4 rows * 66 + 8)
#define GRF4 (16 * GPL4)      // 4352 floats per parity
#define PUB_U32 (2 * 16 * 4 * HH)   // 65536 u32 (256 KB in d_ws)

typedef float f4v __attribute__((ext_vector_type(4)));
typedef float f2v __attribute__((ext_vector_type(2)));
typedef unsigned long long u64;
typedef unsigned int u32;

__device__ __forceinline__ float sigmf(float x)    { return 1.f / (1.f + __expf(-x)); }
__device__ __forceinline__ float tanhfast(float x) { return 1.f - 2.f / (__expf(2.f * x) + 1.f); }

// Thread (w, kap, gt) owns, for every 16-col sub-chunk q=0..7, cols
// [128w+16q+4kap, +4) of gate rows {m*HH + j0 + gt} plus x-cols {8w+2kap, +1}.
__device__ __forceinline__ void load_w(
    const float* __restrict__ Wih, const float* __restrict__ Whh,
    const float* __restrict__ bih, const float* __restrict__ bhh,
    int j0, int w, int kap, int gt,
    f2v w01[4][8], f2v w23[4][8], f2v wxv[4], float bias[4])
{
  #pragma unroll
  for (int m = 0; m < 4; ++m) {
    const int g = m * HH + j0 + gt;
    #pragma unroll
    for (int q = 0; q < 8; ++q) {
      const f4v tw = *(const f4v*)&Whh[g * HH + w * 128 + q * 16 + kap * 4];
      f2v a; a[0] = tw[0]; a[1] = tw[1]; w01[m][q] = a;
      f2v b; b[0] = tw[2]; b[1] = tw[3]; w23[m][q] = b;
    }
    wxv[m]  = *(const f2v*)&Wih[g * FF + w * 8 + kap * 2];
    bias[m] = bih[g] + bhh[g];
  }
}

__global__ void init_ws_kernel(u32* pub) {
  const int i = blockIdx.x * blockDim.x + threadIdx.x;
  if (i < PUB_U32) pub[i] = 0u;   // h = 0.0f, tag byte = 0 (both parities)
}

#define LDU64(P) __hip_atomic_load((P), __ATOMIC_RELAXED, __HIP_MEMORY_SCOPE_AGENT)

// Wait 32-col chunk Q (1 u64/lane: cols 32Q+2gsub,+1) fresh (both tag bytes
// == tg), fast retry (sleep after 2 rounds), strip tags, one 8B LDS write.
#define WAITCH(Q) do {                                                         \
    unsigned lo_ = (unsigned)v[Q], hi_ = (unsigned)(v[Q] >> 32);               \
    int tries = 0;                                                             \
    while ((lo_ & 255u) != tg || (hi_ & 255u) != tg) {                         \
      if (++tries > 2) __builtin_amdgcn_s_sleep(1);                            \
      v[Q] = LDU64((const u64*)(gp + 32 * (Q)));                               \
      lo_ = (unsigned)v[Q]; hi_ = (unsigned)(v[Q] >> 32);                      \
    }                                                                          \
    float2 st_;                                                                \
    st_.x = __uint_as_float(lo_ & ~255u);                                      \
    st_.y = __uint_as_float(hi_ & ~255u);                                      \
    *(float2*)&Us[32 * (Q)] = st_;                                             \
  } while (0)

// FMA on 16-col sub-chunk Q: 4 rows x 4 cols x 4 gates, packed f2v.
#define FMACHUNK(Q) do {                                                       \
    asm volatile("" ::: "memory");                                             \
    _Pragma("unroll")                                                          \
    for (int b = 0; b < 4; ++b) {                                              \
      const f4v u = *(const f4v*)&Up[b * KP + w * 128 + 16 * (Q) + 4 * kap];   \
      f2v u01; u01[0] = u[0]; u01[1] = u[1];                                   \
      f2v u23; u23[0] = u[2]; u23[1] = u[3];                                   \
      _Pragma("unroll")                                                        \
      for (int m = 0; m < 4; ++m)                                              \
        acc2[m][b] += u01 * w01[m][Q] + u23 * w23[m][Q];                       \
    }                                                                          \
  } while (0)

__global__ void __launch_bounds__(NTHR, 1)
lstm_ae_kernel(const float* __restrict__ x,
               const float* __restrict__ eWih, const float* __restrict__ eWhh,
               const float* __restrict__ ebih, const float* __restrict__ ebhh,
               const float* __restrict__ dWih, const float* __restrict__ dWhh,
               const float* __restrict__ dbih, const float* __restrict__ dbhh,
               const float* __restrict__ Wo,  const float* __restrict__ bo,
               float* __restrict__ out, u32* __restrict__ pub)
{
  __shared__ float UA[4 * KP];          // pod A staging: 4 rows x (h|x)
  __shared__ float UB[4 * KP];          // pod B staging
  __shared__ float Gr[2 * GRF4];        // K-split partials, hi-parity

  const int tid = threadIdx.x;
  const int blk = blockIdx.x;
  const int pp  = blk & 7;             // pod-pair group (pods pp, pp+8)
  const int gb  = blk >> 3;            // 0..31: hidden slice j0 = gb*16
  const int j0  = gb * 16;

  const int w    = tid >> 6;           // wave 0..3: owns h cols [128w,+128)
  const int lane = tid & 63;
  const int grow = lane >> 4;          // gather: batch row 0..3
  const int gsub = lane & 15;          // gather: col-pair offset 0..15

  const int ks  = tid >> 4;            // K-slice 0..15
  const int kap = ks & 3;
  const int gt  = tid & 15;

  // Reduce mapping (tid < 64): pair (rb, j0+rjl); c in registers, one per pod.
  const int rb  = tid >> 4, rjl = tid & 15;
  float cA = 0.f, cB = 0.f;

  f2v   w01[4][8], w23[4][8], wxv[4];
  float bias[4];
  load_w(eWih, eWhh, ebih, ebhh, j0, w, kap, gt, w01, w23, wxv, bias);

  u64 v[4];
  {  // prologue: issue pod A step 0 gather (parity 0, tags 0 from init)
    const u32* gpn = pub + (size_t)pp * (4 * HH) + grow * HH + 128 * w + 2 * gsub;
    v[0] = LDU64((const u64*)(gpn + 0));
    v[1] = LDU64((const u64*)(gpn + 32));
    v[2] = LDU64((const u64*)(gpn + 64));
    v[3] = LDU64((const u64*)(gpn + 96));
  }

  #pragma unroll 1
  for (int hi = 0; hi < 4 * TT; ++hi) {          // 2048 half-iterations
    if (hi == 2 * TT)                            // encoder -> decoder weights
      load_w(dWih, dWhh, dbih, dbhh, j0, w, kap, gt, w01, w23, wxv, bias);

    const int sg     = hi >> 1;                  // global step 0..1023
    const int podbit = hi & 1;
    const int phase  = sg >> 9;
    const int step   = sg & 511;
    const int t      = phase ? (511 - step) : step;
    const unsigned tg = (unsigned)(sg & 255);
    const int podid  = pp + (podbit << 3);
    const int b0     = podid * 4;
    float* Up = podbit ? UB : UA;
    const u32* prd = pub + (size_t)((sg & 1) * 16 + podid) * (4 * HH);
    u32*       pwr = pub + (size_t)(((sg + 1) & 1) * 16 + podid) * (4 * HH);
    float* Grp = Gr + (hi & 1) * GRF4;

    // ---- stage this wave's x slice (cols [8w,+8), 4 rows; lanes<32) ----
    if (lane < 32) {
      const int xr = lane >> 3, xs = lane & 7;
      Up[xr * KP + HH + 8 * w + xs] =
          x[((size_t)(b0 + xr) * TT + t) * FF + 8 * w + xs];
    }

    f2v acc2[4][4];
    #pragma unroll
    for (int m = 0; m < 4; ++m)
      #pragma unroll
      for (int b = 0; b < 4; ++b) {
        f2v z; z[0] = (ks == 0) ? bias[m] : 0.f; z[1] = 0.f;
        acc2[m][b] = z;
      }

    // ---- gather (early-issued last half-iter) -> FMA pipeline ----
    const u32* gp = prd + grow * HH + 128 * w + 2 * gsub;
    float*     Us = Up + grow * KP + 128 * w + 2 * gsub;
    WAITCH(0); FMACHUNK(0); FMACHUNK(1);
    WAITCH(1); FMACHUNK(2); FMACHUNK(3);
    WAITCH(2); FMACHUNK(4); FMACHUNK(5);
    WAITCH(3); FMACHUNK(6); FMACHUNK(7);

    // ---- x part (packed) ----
    #pragma unroll
    for (int b = 0; b < 4; ++b) {
      const f2v ux = *(const f2v*)&Up[b * KP + HH + 8 * w + 2 * kap];
      #pragma unroll
      for (int m = 0; m < 4; ++m)
        acc2[m][b] += ux * wxv[m];
    }
    {
      float* Gw = Grp + ks * GPL4 + gt;
      #pragma unroll
      for (int b = 0; b < 4; ++b)
        #pragma unroll
        for (int m = 0; m < 4; ++m)
          Gw[b * GRS + m * 16] = acc2[m][b][0] + acc2[m][b][1];
    }
    __syncthreads();   // the one barrier per half-iteration

    // ---- reduce 16 K-planes, activations, update, mantissa-tag publish ----
    if (tid < 64) {
      const float* g0 = Grp + rb * GRS + rjl;
      float si = 0.f, sf = 0.f, sgg = 0.f, so = 0.f;
      #pragma unroll
      for (int q = 0; q < 16; ++q) {
        const float* g = g0 + q * GPL4;
        si += g[0]; sf += g[16]; sgg += g[32]; so += g[48];
      }
      const float c_old = podbit ? cB : cA;
      const float c2 = sigmf(sf) * c_old + sigmf(si) * tanhfast(sgg);
      const float h2 = sigmf(so) * tanhfast(c2);
      if (podbit) cB = c2; else cA = c2;
      const unsigned pk = (__float_as_uint(h2) & ~255u)
                        | ((unsigned)(sg + 1) & 255u);
      __hip_atomic_store(&pwr[rb * HH + j0 + rjl], pk,
                         __ATOMIC_RELAXED, __HIP_MEMORY_SCOPE_AGENT);
    }

    // ---- decoder out-projection: wave w = full 512-dot of row w (pre-update
    // h(t), post-BAR so all staging visible), 6-round shfl, direct store ----
    if (phase) {
      const float* Ur = Up + w * KP + lane * 8;
      const float* Wr = Wo + gb * HH + lane * 8;
      const f4v u0 = *(const f4v*)(Ur);
      const f4v u1 = *(const f4v*)(Ur + 4);
      const f4v q0 = *(const f4v*)(Wr);
      const f4v q1 = *(const f4v*)(Wr + 4);
      float pj = u0[0]*q0[0] + u0[1]*q0[1] + u0[2]*q0[2] + u0[3]*q0[3]
               + u1[0]*q1[0] + u1[1]*q1[1] + u1[2]*q1[2] + u1[3]*q1[3];
      pj += __shfl_xor(pj, 1);
      pj += __shfl_xor(pj, 2);
      pj += __shfl_xor(pj, 4);
      pj += __shfl_xor(pj, 8);
      pj += __shfl_xor(pj, 16);
      pj += __shfl_xor(pj, 32);
      if (lane == 0)
        out[((size_t)(b0 + w) * TT + t) * FF + gb] = pj + bo[gb];
    }

    // ---- EARLY ISSUE for hi+1 (the OTHER pod): its publish happened one
    // half-iter ago -> visible; loads arrive fresh by the next WAITCH. ----
    {
      const int hin = hi + 1;
      const int sgn = hin >> 1, pbn = hin & 1;
      const int podn = pp + (pbn << 3);
      const u32* gpn = pub + (size_t)((sgn & 1) * 16 + podn) * (4 * HH)
                     + grow * HH + 128 * w + 2 * gsub;
      v[0] = LDU64((const u64*)(gpn + 0));
      v[1] = LDU64((const u64*)(gpn + 32));
      v[2] = LDU64((const u64*)(gpn + 64));
      v[3] = LDU64((const u64*)(gpn + 96));
      asm volatile("" ::: "memory");
    }
  }
}

extern "C" void kernel_launch(void* const* d_in, const int* in_sizes, int n_in,
                              void* d_out, int out_size, void* d_ws, size_t ws_size,
                              hipStream_t stream) {
  const float* x    = (const float*)d_in[0];
  const float* eWih = (const float*)d_in[1];   // enc_Wih0 [2048,32]
  const float* eWhh = (const float*)d_in[2];   // enc_Whh0 [2048,512]
  const float* ebih = (const float*)d_in[3];
  const float* ebhh = (const float*)d_in[4];
  // d_in[5..8] enc layer 1: dead (only feeds dead decoder layer 1)
  const float* dWih = (const float*)d_in[9];   // dec_Wih0
  const float* dWhh = (const float*)d_in[10];  // dec_Whh0
  const float* dbih = (const float*)d_in[11];
  const float* dbhh = (const float*)d_in[12];
  // d_in[13..16] dec layer 1: dead (hB/cB never reach outs)
  const float* Wo   = (const float*)d_in[17];  // [32,512]
  const float* bo   = (const float*)d_in[18];  // [32]
  float* out = (float*)d_out;

  u32* pubbuf = (u32*)d_ws;                    // [2][16][4][512] tagged h (u32)

  init_ws_kernel<<<dim3((PUB_U32 + NTHR - 1) / NTHR), dim3(NTHR), 0, stream>>>(pubbuf);
  lstm_ae_kernel<<<dim3(NBLK), dim3(NTHR), 0, stream>>>(
      x, eWih, eWhh, ebih, ebhh, dWih, dWhh, dbih, dbhh, Wo, bo,
      out, pubbuf);
}